// Round 2
// baseline (156.394 us; speedup 1.0000x reference)
//
#include <hip/hip_runtime.h>
#include <cmath>

typedef unsigned int u32;
typedef unsigned long long u64;

// 64 theta values = powf(10000f, -i/64) computed on HOST with glibc powf
// (same implementation the XLA constant-folder / HloEvaluator used on the
// driver), passed by value through kernarg.
struct ThetaArr { float t[64]; };

// glibc sysdeps/ieee754/flt-32 __inv_pio4 table (192-bit 4/pi, byte-sliding).
__device__ const u32 g_inv_pio4[24] = {
  0x000000a2u, 0x0000a2f9u, 0x00a2f983u, 0xa2f9836eu,
  0xf9836e4eu, 0x836e4e44u, 0x6e4e4415u, 0x4e441529u,
  0x441529fcu, 0x1529fc27u, 0x29fc2757u, 0xfc2757d1u,
  0x2757d1f5u, 0x57d1f534u, 0xd1f534ddu, 0xf534ddc0u,
  0x34ddc0dbu, 0xddc0db62u, 0xc0db6295u, 0xdb629599u,
  0x6295993cu, 0x95993c43u, 0x993c4390u, 0x3c439041u
};

// glibc sinf_poly, even (sine) branch. Double precision, fma placement
// mirrors gcc -mfma contraction of the glibc C source.
__device__ __forceinline__ double sin_poly_d(double x, double x2) {
#pragma clang fp contract(off)
  const double s1 = -0x1.555545995a603p-3;
  const double s2 =  0x1.1107605230bc4p-7;
  const double s3 = -0x1.994eb3774cf24p-13;
  double x3  = x * x2;
  double s1v = __builtin_fma(x2, s3, s2);     // s2 + x2*s3
  double x7  = x3 * x2;                       // x^5
  double s   = __builtin_fma(x3, s1, x);      // x + x3*s1
  return __builtin_fma(x7, s1v, s);           // s + x7*s1v
}

// glibc sinf_poly, odd (cosine) branch.
__device__ __forceinline__ double cos_poly_d(double x2) {
#pragma clang fp contract(off)
  const double c0 =  1.0;
  const double c1 = -0x1.ffffffd0c621cp-2;
  const double c2 =  0x1.55553e1068f19p-5;
  const double c3 = -0x1.6c087e89a359dp-10;
  const double c4 =  0x1.99343027bf8c3p-16;
  double x4  = x2 * x2;
  double c2v = __builtin_fma(x2, c4, c3);     // c3 + x2*c4
  double c1v = __builtin_fma(x2, c1, c0);     // c0 + x2*c1
  double x6  = x4 * x2;
  double cv  = __builtin_fma(x4, c2, c1v);    // c1v + x4*c2
  return __builtin_fma(x6, c2v, cv);          // cv + x6*c2v
}

// Bit-exact port of glibc (>=2.28) __sinf / __cosf for y >= 0, y < 2^12.
// Branch structure, reductions, tables and rounding order follow
// sysdeps/ieee754/flt-32/{s_sinf.c,s_cosf.c,sincosf.h,s_sincosf_data.c}.
// Sign handling is factored algebraically (poly(±x) = ±poly(x) exactly;
// table[1] = exact negation of cos coeffs), which is bit-identical.
__device__ __forceinline__ void sincosf_glibc(float y, float& sf, float& cf) {
#pragma clang fp contract(off)
  const double hpi_inv = 0x1.45F306DC9C883p+23;  // 2/pi * 2^24
  const double hpi     = 0x1.921FB54442D18p0;    // pi/2
  const double pi63    = 0x1.921FB54442D18p-62;  // pi * 2^-63
  u32 xi = __float_as_uint(y);
  u32 abstop = (xi >> 20) & 0x7ffu;              // abstop12
  double x = (double)y;
  if (abstop < 0x398u) {                         // |y| < 2^-12
    sf = y; cf = 1.0f; return;
  }
  if (abstop < 0x3f4u) {                         // |y| < ~pi/4
    double x2 = x * x;
    sf = (float)sin_poly_d(x, x2);
    cf = (float)cos_poly_d(x2);
    return;
  }
  int n;
  double xr;
  if (abstop < 0x42fu) {                         // |y| < ~120: reduce_fast
    double r = x * hpi_inv;
    n = (((int)r) + 0x800000) >> 24;
    xr = __builtin_fma(-(double)n, hpi, x);      // x - n*hpi (fnma, as -mfma build)
  } else {                                       // 120 <= y < 4096: reduce_large
    int idx = (xi >> 26) & 15;
    int sh  = (xi >> 23) & 7;
    u32 xm  = ((xi & 0xffffffu) | 0x800000u) << sh;
    u64 res0 = (u64)(u32)(xm * g_inv_pio4[idx]);      // low-32 wrap, as glibc
    u64 res1 = (u64)xm * (u64)g_inv_pio4[idx + 4];
    u64 res2 = (u64)xm * (u64)g_inv_pio4[idx + 8];
    res0 = ((res2 >> 32) | (res0 << 32)) + res1;
    u64 nn = (res0 + (1ull << 61)) >> 62;
    res0 -= nn << 62;
    double xd = (double)(long long)res0;
    xr = xd * pi63;
    n = (int)nn;
  }
  double x2 = xr * xr;
  double sp = sin_poly_d(xr, x2);
  double cp = cos_poly_d(x2);
  float spf = (float)sp, cpf = (float)cp;
  bool flip = (n & 2) != 0;
  float sres, cres;
  if (n & 1) {
    // sin -> cos branch (sign via table select); cos -> sine branch (sign via sgn[(n+1)&3])
    sres = flip ? -cpf : cpf;
    cres = flip ?  spf : -spf;
  } else {
    sres = flip ? -spf : spf;
    cres = flip ? -cpf : cpf;
  }
  sf = sres; cf = cres;
}

__global__ __launch_bounds__(256) void spike_rope_kernel(
    const float* __restrict__ xin, const int* __restrict__ position,
    float* __restrict__ outp, ThetaArr th, int npairs)
{
#pragma clang fp contract(off)
  int t = blockIdx.x * blockDim.x + threadIdx.x;
  if (t >= npairs) return;
  int b = t >> 6;          // row (wave-uniform: 64 lanes = one row)
  int i = t & 63;          // pair index in [0,64)
  size_t e1 = (size_t)(b * 128 + i);
  size_t e2 = e1 + 64;
  const uint4* p1 = (const uint4*)(xin + (e1 << 5));
  const uint4* p2 = (const uint4*)(xin + (e2 << 5));

  // decode: pulse float (0.0f/1.0f) -> bit via (asuint>>23)&1, MSB-first pack
  u32 w1 = 0, w2 = 0;
#pragma unroll
  for (int k = 0; k < 8; ++k) {
    uint4 v = p1[k];
    u32 nib = (((v.x >> 23) & 1u) << 3) | (((v.y >> 23) & 1u) << 2) |
              (((v.z >> 23) & 1u) << 1) | ((v.w >> 23) & 1u);
    w1 = (w1 << 4) | nib;
  }
#pragma unroll
  for (int k = 0; k < 8; ++k) {
    uint4 v = p2[k];
    u32 nib = (((v.x >> 23) & 1u) << 3) | (((v.y >> 23) & 1u) << 2) |
              (((v.z >> 23) & 1u) << 1) | ((v.w >> 23) & 1u);
    w2 = (w2 << 4) | nib;
  }
  float x1 = __uint_as_float(w1);
  float x2 = __uint_as_float(w2);

  float pf = (float)position[b];     // int32 -> f32, exact
  float theta = th.t[i];             // glibc powf value from host
  float ang = pf * theta;            // single f32 mul, contract off
  float sv, cv;
  sincosf_glibc(ang, sv, cv);

  // reference: r1 = x1*cos + (-x2)*sin ; r2 = x2*cos + x1*sin  (NO fma)
  float r1 = (x1 * cv) + ((-x2) * sv);
  float r2 = (x2 * cv) + (x1 * sv);

  u32 o1 = __float_as_uint(r1);
  u32 o2 = __float_as_uint(r2);
  uint4* q1 = (uint4*)(outp + (e1 << 5));
  uint4* q2 = (uint4*)(outp + (e2 << 5));
#pragma unroll
  for (int k = 0; k < 8; ++k) {
    int s0 = 31 - 4 * k;
    uint4 v;
    v.x = ((o1 >> s0) & 1u)       ? 0x3f800000u : 0u;
    v.y = ((o1 >> (s0 - 1)) & 1u) ? 0x3f800000u : 0u;
    v.z = ((o1 >> (s0 - 2)) & 1u) ? 0x3f800000u : 0u;
    v.w = ((o1 >> (s0 - 3)) & 1u) ? 0x3f800000u : 0u;
    q1[k] = v;
  }
#pragma unroll
  for (int k = 0; k < 8; ++k) {
    int s0 = 31 - 4 * k;
    uint4 v;
    v.x = ((o2 >> s0) & 1u)       ? 0x3f800000u : 0u;
    v.y = ((o2 >> (s0 - 1)) & 1u) ? 0x3f800000u : 0u;
    v.z = ((o2 >> (s0 - 2)) & 1u) ? 0x3f800000u : 0u;
    v.w = ((o2 >> (s0 - 3)) & 1u) ? 0x3f800000u : 0u;
    q2[k] = v;
  }
}

extern "C" void kernel_launch(void* const* d_in, const int* in_sizes, int n_in,
                              void* d_out, int out_size, void* d_ws, size_t ws_size,
                              hipStream_t stream) {
  const float* x = (const float*)d_in[0];
  const int* position = (const int*)d_in[1];
  float* out = (float*)d_out;
  int batch = in_sizes[1];          // position count = BATCH
  int npairs = batch * 64;

  // theta[i] = powf(10000f, (-2f*i)/128f) via the runtime glibc powf.
  // volatile fn-pointer defeats LLVM constant folding (which would use
  // a correctly-rounded double pow instead of glibc's powf).
  ThetaArr th;
  float (*volatile pfn)(float, float) = &powf;
  for (int i = 0; i < 64; ++i) {
    float e = (-2.0f * (float)i) / 128.0f;   // exact in f32, matches jax
    th.t[i] = pfn(10000.0f, e);
  }

  int threads = 256;
  int blocks = (npairs + threads - 1) / threads;
  spike_rope_kernel<<<blocks, threads, 0, stream>>>(x, position, out, th, npairs);
}

// Round 3
// 110.613 us; speedup vs baseline: 1.4139x; 1.4139x over previous
//
#include <hip/hip_runtime.h>
#include <cmath>

typedef unsigned int u32;
typedef unsigned long long u64;

// 64 theta values = powf(10000f, -i/64) computed on HOST with glibc powf
// (same implementation the XLA constant-folder used), passed via kernarg.
struct ThetaArr { float t[64]; };

// glibc sysdeps/ieee754/flt-32 __inv_pio4 table (192-bit 4/pi, byte-sliding).
__device__ const u32 g_inv_pio4[24] = {
  0x000000a2u, 0x0000a2f9u, 0x00a2f983u, 0xa2f9836eu,
  0xf9836e4eu, 0x836e4e44u, 0x6e4e4415u, 0x4e441529u,
  0x441529fcu, 0x1529fc27u, 0x29fc2757u, 0xfc2757d1u,
  0x2757d1f5u, 0x57d1f534u, 0xd1f534ddu, 0xf534ddc0u,
  0x34ddc0dbu, 0xddc0db62u, 0xc0db6295u, 0xdb629599u,
  0x6295993cu, 0x95993c43u, 0x993c4390u, 0x3c439041u
};

__device__ __forceinline__ double sin_poly_d(double x, double x2) {
#pragma clang fp contract(off)
  const double s1 = -0x1.555545995a603p-3;
  const double s2 =  0x1.1107605230bc4p-7;
  const double s3 = -0x1.994eb3774cf24p-13;
  double x3  = x * x2;
  double s1v = __builtin_fma(x2, s3, s2);
  double x7  = x3 * x2;
  double s   = __builtin_fma(x3, s1, x);
  return __builtin_fma(x7, s1v, s);
}

__device__ __forceinline__ double cos_poly_d(double x2) {
#pragma clang fp contract(off)
  const double c0 =  1.0;
  const double c1 = -0x1.ffffffd0c621cp-2;
  const double c2 =  0x1.55553e1068f19p-5;
  const double c3 = -0x1.6c087e89a359dp-10;
  const double c4 =  0x1.99343027bf8c3p-16;
  double x4  = x2 * x2;
  double c2v = __builtin_fma(x2, c4, c3);
  double c1v = __builtin_fma(x2, c1, c0);
  double x6  = x4 * x2;
  double cv  = __builtin_fma(x4, c2, c1v);
  return __builtin_fma(x6, c2v, cv);
}

// Bit-exact port of glibc (>=2.28) __sinf/__cosf for 0 <= y < 2^12.
// Verified absmax == 0.0 on hardware (Round 2 bench).
__device__ __forceinline__ void sincosf_glibc(float y, float& sf, float& cf) {
#pragma clang fp contract(off)
  const double hpi_inv = 0x1.45F306DC9C883p+23;
  const double hpi     = 0x1.921FB54442D18p0;
  const double pi63    = 0x1.921FB54442D18p-62;
  u32 xi = __float_as_uint(y);
  u32 abstop = (xi >> 20) & 0x7ffu;
  double x = (double)y;
  if (abstop < 0x398u) { sf = y; cf = 1.0f; return; }
  if (abstop < 0x3f4u) {
    double x2 = x * x;
    sf = (float)sin_poly_d(x, x2);
    cf = (float)cos_poly_d(x2);
    return;
  }
  int n;
  double xr;
  if (abstop < 0x42fu) {                         // reduce_fast
    double r = x * hpi_inv;
    n = (((int)r) + 0x800000) >> 24;
    xr = __builtin_fma(-(double)n, hpi, x);
  } else {                                       // reduce_large
    int idx = (xi >> 26) & 15;
    int sh  = (xi >> 23) & 7;
    u32 xm  = ((xi & 0xffffffu) | 0x800000u) << sh;
    u64 res0 = (u64)(u32)(xm * g_inv_pio4[idx]);
    u64 res1 = (u64)xm * (u64)g_inv_pio4[idx + 4];
    u64 res2 = (u64)xm * (u64)g_inv_pio4[idx + 8];
    res0 = ((res2 >> 32) | (res0 << 32)) + res1;
    u64 nn = (res0 + (1ull << 61)) >> 62;
    res0 -= nn << 62;
    double xd = (double)(long long)res0;
    xr = xd * pi63;
    n = (int)nn;
  }
  double x2 = xr * xr;
  double sp = sin_poly_d(xr, x2);
  double cp = cos_poly_d(x2);
  float spf = (float)sp, cpf = (float)cp;
  bool flip = (n & 2) != 0;
  float sres, cres;
  if (n & 1) {
    sres = flip ? -cpf : cpf;
    cres = flip ?  spf : -spf;
  } else {
    sres = flip ? -spf : spf;
    cres = flip ? -cpf : cpf;
  }
  sf = sres; cf = cres;
}

// Block = 256 threads = 2 rows. Coalesced global <-> LDS-transposed decode.
// LDS slot swizzle: logical chunk c of element e lives at slot e*8 + (c ^ (e&7))
// so both the chunk-major staging writes and the element-major decode reads
// spread evenly over all 32 banks (minimal bank cycles, no conflicts).
__global__ __launch_bounds__(256) void spike_rope_kernel(
    const float* __restrict__ xin, const int* __restrict__ position,
    float* __restrict__ outp, ThetaArr th, int batch)
{
#pragma clang fp contract(off)
  __shared__ uint4 stage[2048];   // 32 KiB: 2 rows of pulses, swizzled
  __shared__ u32 words[256];      // decoded input words (one per element)
  __shared__ u32 owords[256];     // encoded output words

  const int t = (int)threadIdx.x;
  const int blk = (int)blockIdx.x;
  const size_t base_chunk = (size_t)blk * 2048;          // 16B chunks
  const size_t total_chunks = (size_t)batch * 1024;      // batch*128*8
  const uint4* gx = (const uint4*)xin;

  // ---- Phase A: coalesced stage-in (1 KiB per wave per instr) ----
#pragma unroll
  for (int m = 0; m < 8; ++m) {
    int idx = m * 256 + t;                // local chunk 0..2047
    size_t gc = base_chunk + (size_t)idx;
    uint4 v;
    if (gc < total_chunks) v = gx[gc];
    else { v.x = v.y = v.z = v.w = 0u; }
    int e = idx >> 3;                     // local element 0..255
    int c = idx & 7;                      // chunk-in-element
    stage[(e << 3) | (c ^ (e & 7))] = v;
  }
  __syncthreads();

  // ---- Phase B: decode one element per thread (swizzled LDS reads) ----
  u32 w = 0;
#pragma unroll
  for (int k = 0; k < 8; ++k) {
    uint4 v = stage[(t << 3) | (k ^ (t & 7))];
    u32 nib = (((v.x >> 23) & 1u) << 3) | (((v.y >> 23) & 1u) << 2) |
              (((v.z >> 23) & 1u) << 1) | ((v.w >> 23) & 1u);
    w = (w << 4) | nib;
  }
  words[t] = w;
  __syncthreads();

  // ---- Phase C: fp32 RoPE on the decoded words (bit-exact path) ----
  {
    int row_loc = t >> 7;                 // 0 or 1 (wave-uniform)
    int j = t & 127;                      // output dim
    int i = j & 63;                       // pair index
    u32 x1w = words[(row_loc << 7) | i];
    u32 x2w = words[(row_loc << 7) | i | 64];
    int grow = blk * 2 + row_loc;
    int pos = (grow < batch) ? position[grow] : 0;
    float pf = (float)pos;                // exact int->f32
    float ang = pf * th.t[i];             // single f32 mul
    float sv, cv;
    sincosf_glibc(ang, sv, cv);
    float x1 = __uint_as_float(x1w);
    float x2 = __uint_as_float(x2w);
    // reference: r1 = x1*cos + (-x2)*sin ; r2 = x2*cos + x1*sin (NO fma)
    float r = (j < 64) ? ((x1 * cv) + ((-x2) * sv))
                       : ((x2 * cv) + (x1 * sv));
    owords[t] = __float_as_uint(r);
  }
  __syncthreads();

  // ---- Phase D: coalesced encode + stage-out ----
  uint4* gy = (uint4*)outp;
#pragma unroll
  for (int m = 0; m < 8; ++m) {
    int idx = m * 256 + t;
    size_t gc = base_chunk + (size_t)idx;
    if (gc >= total_chunks) continue;
    int e = idx >> 3;
    int c = idx & 7;
    u32 ow = owords[e];                   // 8 lanes/word -> LDS broadcast
    int s0 = 31 - (c << 2);
    uint4 v;
    v.x = ((ow >> s0) & 1u)       ? 0x3f800000u : 0u;
    v.y = ((ow >> (s0 - 1)) & 1u) ? 0x3f800000u : 0u;
    v.z = ((ow >> (s0 - 2)) & 1u) ? 0x3f800000u : 0u;
    v.w = ((ow >> (s0 - 3)) & 1u) ? 0x3f800000u : 0u;
    gy[gc] = v;
  }
}

extern "C" void kernel_launch(void* const* d_in, const int* in_sizes, int n_in,
                              void* d_out, int out_size, void* d_ws, size_t ws_size,
                              hipStream_t stream) {
  const float* x = (const float*)d_in[0];
  const int* position = (const int*)d_in[1];
  float* out = (float*)d_out;
  int batch = in_sizes[1];

  // theta[i] = powf(10000f, -2f*i/128f) via the runtime glibc powf.
  // volatile fn-pointer defeats LLVM constant folding.
  ThetaArr th;
  float (*volatile pfn)(float, float) = &powf;
  for (int i = 0; i < 64; ++i) {
    float e = (-2.0f * (float)i) / 128.0f;
    th.t[i] = pfn(10000.0f, e);
  }

  int blocks = (batch + 1) / 2;     // 2 rows per block
  spike_rope_kernel<<<blocks, 256, 0, stream>>>(x, position, out, th, batch);
}

// Round 4
// 106.876 us; speedup vs baseline: 1.4633x; 1.0350x over previous
//
#include <hip/hip_runtime.h>
#include <cmath>

typedef unsigned int u32;
typedef unsigned long long u64;

// 64 theta values = powf(10000f, -i/64) computed on HOST with glibc powf
// (same implementation the XLA constant-folder used), passed via kernarg.
struct ThetaArr { float t[64]; };

// glibc sysdeps/ieee754/flt-32 __inv_pio4 table (192-bit 4/pi, byte-sliding).
__device__ const u32 g_inv_pio4[24] = {
  0x000000a2u, 0x0000a2f9u, 0x00a2f983u, 0xa2f9836eu,
  0xf9836e4eu, 0x836e4e44u, 0x6e4e4415u, 0x4e441529u,
  0x441529fcu, 0x1529fc27u, 0x29fc2757u, 0xfc2757d1u,
  0x2757d1f5u, 0x57d1f534u, 0xd1f534ddu, 0xf534ddc0u,
  0x34ddc0dbu, 0xddc0db62u, 0xc0db6295u, 0xdb629599u,
  0x6295993cu, 0x95993c43u, 0x993c4390u, 0x3c439041u
};

__device__ __forceinline__ double sin_poly_d(double x, double x2) {
#pragma clang fp contract(off)
  const double s1 = -0x1.555545995a603p-3;
  const double s2 =  0x1.1107605230bc4p-7;
  const double s3 = -0x1.994eb3774cf24p-13;
  double x3  = x * x2;
  double s1v = __builtin_fma(x2, s3, s2);
  double x7  = x3 * x2;
  double s   = __builtin_fma(x3, s1, x);
  return __builtin_fma(x7, s1v, s);
}

__device__ __forceinline__ double cos_poly_d(double x2) {
#pragma clang fp contract(off)
  const double c0 =  1.0;
  const double c1 = -0x1.ffffffd0c621cp-2;
  const double c2 =  0x1.55553e1068f19p-5;
  const double c3 = -0x1.6c087e89a359dp-10;
  const double c4 =  0x1.99343027bf8c3p-16;
  double x4  = x2 * x2;
  double c2v = __builtin_fma(x2, c4, c3);
  double c1v = __builtin_fma(x2, c1, c0);
  double x6  = x4 * x2;
  double cv  = __builtin_fma(x4, c2, c1v);
  return __builtin_fma(x6, c2v, cv);
}

// Bit-exact port of glibc (>=2.28) __sinf/__cosf for 0 <= y < 2^12.
// Verified absmax == 0.0 on hardware (Rounds 2 and 3).
__device__ __forceinline__ void sincosf_glibc(float y, float& sf, float& cf) {
#pragma clang fp contract(off)
  const double hpi_inv = 0x1.45F306DC9C883p+23;
  const double hpi     = 0x1.921FB54442D18p0;
  const double pi63    = 0x1.921FB54442D18p-62;
  u32 xi = __float_as_uint(y);
  u32 abstop = (xi >> 20) & 0x7ffu;
  double x = (double)y;
  if (abstop < 0x398u) { sf = y; cf = 1.0f; return; }
  if (abstop < 0x3f4u) {
    double x2 = x * x;
    sf = (float)sin_poly_d(x, x2);
    cf = (float)cos_poly_d(x2);
    return;
  }
  int n;
  double xr;
  if (abstop < 0x42fu) {                         // reduce_fast
    double r = x * hpi_inv;
    n = (((int)r) + 0x800000) >> 24;
    xr = __builtin_fma(-(double)n, hpi, x);
  } else {                                       // reduce_large
    int idx = (xi >> 26) & 15;
    int sh  = (xi >> 23) & 7;
    u32 xm  = ((xi & 0xffffffu) | 0x800000u) << sh;
    u64 res0 = (u64)(u32)(xm * g_inv_pio4[idx]);
    u64 res1 = (u64)xm * (u64)g_inv_pio4[idx + 4];
    u64 res2 = (u64)xm * (u64)g_inv_pio4[idx + 8];
    res0 = ((res2 >> 32) | (res0 << 32)) + res1;
    u64 nn = (res0 + (1ull << 61)) >> 62;
    res0 -= nn << 62;
    double xd = (double)(long long)res0;
    xr = xd * pi63;
    n = (int)nn;
  }
  double x2 = xr * xr;
  double sp = sin_poly_d(xr, x2);
  double cp = cos_poly_d(x2);
  float spf = (float)sp, cpf = (float)cp;
  bool flip = (n & 2) != 0;
  float sres, cres;
  if (n & 1) {
    sres = flip ? -cpf : cpf;
    cres = flip ?  spf : -spf;
  } else {
    sres = flip ? -spf : spf;
    cres = flip ? -cpf : cpf;
  }
  sf = sres; cf = cres;
}

// Wave-autonomous version: one 64-lane wave owns one row (128 elements),
// no LDS storage, no __syncthreads. Element transpose done in registers:
//  - decode: per 256-float chunk s, lane l holds pulses (l&7)*4..+3 of
//    element s*8+(l>>3); nibble placed at bit 28-(l&7)*4; 3-step shfl_xor
//    OR-reduce over the 8-lane element group; one bpermute (src 8*(l&7))
//    routes element i (iter i>>3) and i+64 (iter 8+(i>>3)) to owner lane i.
//  - encode: exact transpose, src lane (s&7)*8 + (l>>3).
__global__ __launch_bounds__(256, 4) void spike_rope_kernel(
    const float* __restrict__ xin, const int* __restrict__ position,
    float* __restrict__ outp, ThetaArr th, int batch)
{
#pragma clang fp contract(off)
  const int t = (int)threadIdx.x;
  const int lane = t & 63;
  const int wid = t >> 6;
  const int row = (int)blockIdx.x * 4 + wid;
  if (row >= batch) return;

  const int grp = lane >> 3;        // element sub-index within chunk (0..7)
  const int sub = lane & 7;         // 4-pulse slot within element (0..7)
  const int j0  = sub << 2;         // first pulse index this lane holds
  const int shN = 28 - j0;          // nibble placement shift (decode)
  const int sh0 = 31 - j0;          // first bit shift (encode)
  const int dsrc = sub << 3;        // decode route source lane

  // ---- load full row, coalesced (each instr: 64 lanes x 16B = 1KiB) ----
  const uint4* rowp = (const uint4*)(xin + (size_t)row * 4096);
  uint4 v[16];
#pragma unroll
  for (int s = 0; s < 16; ++s) v[s] = rowp[s * 64 + lane];

  // ---- in-register transpose + decode ----
  u32 x1w = 0, x2w = 0;
#pragma unroll
  for (int s = 0; s < 16; ++s) {
    uint4 q = v[s];
    u32 nib = (((q.x >> 23) & 1u) << 3) | (((q.y >> 23) & 1u) << 2) |
              (((q.z >> 23) & 1u) << 1) | ((q.w >> 23) & 1u);
    u32 part = nib << shN;
    part |= (u32)__shfl_xor((int)part, 1, 64);
    part |= (u32)__shfl_xor((int)part, 2, 64);
    part |= (u32)__shfl_xor((int)part, 4, 64);
    u32 full = (u32)__shfl((int)part, dsrc, 64);
    if (s < 8) { if (grp == s)     x1w = full; }
    else       { if (grp == s - 8) x2w = full; }
  }

  // ---- bit-exact fp32 RoPE (verified path, unchanged) ----
  float pf = (float)position[row];   // exact int->f32
  float ang = pf * th.t[lane];       // single f32 mul
  float sv, cv;
  sincosf_glibc(ang, sv, cv);
  float x1 = __uint_as_float(x1w);
  float x2 = __uint_as_float(x2w);
  // reference: r1 = x1*cos + (-x2)*sin ; r2 = x2*cos + x1*sin (NO fma)
  float r1 = (x1 * cv) + ((-x2) * sv);
  float r2 = (x2 * cv) + (x1 * sv);
  u32 o1 = __float_as_uint(r1);
  u32 o2 = __float_as_uint(r2);

  // ---- in-register transpose + encode + coalesced store ----
  uint4* orow = (uint4*)(outp + (size_t)row * 4096);
#pragma unroll
  for (int s = 0; s < 16; ++s) {
    int sl = ((s & 7) << 3) + grp;             // source lane holding element
    u32 ow = (u32)__shfl((int)(s < 8 ? o1 : o2), sl, 64);
    uint4 w;
    w.x = ((ow >> sh0) & 1u)       ? 0x3f800000u : 0u;
    w.y = ((ow >> (sh0 - 1)) & 1u) ? 0x3f800000u : 0u;
    w.z = ((ow >> (sh0 - 2)) & 1u) ? 0x3f800000u : 0u;
    w.w = ((ow >> (sh0 - 3)) & 1u) ? 0x3f800000u : 0u;
    orow[s * 64 + lane] = w;
  }
}

extern "C" void kernel_launch(void* const* d_in, const int* in_sizes, int n_in,
                              void* d_out, int out_size, void* d_ws, size_t ws_size,
                              hipStream_t stream) {
  const float* x = (const float*)d_in[0];
  const int* position = (const int*)d_in[1];
  float* out = (float*)d_out;
  int batch = in_sizes[1];

  // theta[i] = powf(10000f, -2f*i/128f) via the runtime glibc powf.
  // volatile fn-pointer defeats LLVM constant folding.
  ThetaArr th;
  float (*volatile pfn)(float, float) = &powf;
  for (int i = 0; i < 64; ++i) {
    float e = (-2.0f * (float)i) / 128.0f;
    th.t[i] = pfn(10000.0f, e);
  }

  int blocks = (batch + 3) / 4;     // 4 rows (waves) per 256-thread block
  spike_rope_kernel<<<blocks, 256, 0, stream>>>(x, position, out, th, batch);
}

// Round 6
// 84.117 us; speedup vs baseline: 1.8592x; 1.2706x over previous
//
#include <hip/hip_runtime.h>
#include <cmath>

typedef unsigned int u32;
typedef unsigned long long u64;
typedef u32 v4u __attribute__((ext_vector_type(4)));   // native vec for NT ops

// 64 theta values = powf(10000f, -i/64) computed on HOST with glibc powf
// (same implementation the XLA constant-folder used), passed via kernarg.
struct ThetaArr { float t[64]; };

// glibc sysdeps/ieee754/flt-32 __inv_pio4 table (192-bit 4/pi, byte-sliding).
__device__ const u32 g_inv_pio4[24] = {
  0x000000a2u, 0x0000a2f9u, 0x00a2f983u, 0xa2f9836eu,
  0xf9836e4eu, 0x836e4e44u, 0x6e4e4415u, 0x4e441529u,
  0x441529fcu, 0x1529fc27u, 0x29fc2757u, 0xfc2757d1u,
  0x2757d1f5u, 0x57d1f534u, 0xd1f534ddu, 0xf534ddc0u,
  0x34ddc0dbu, 0xddc0db62u, 0xc0db6295u, 0xdb629599u,
  0x6295993cu, 0x95993c43u, 0x993c4390u, 0x3c439041u
};

__device__ __forceinline__ double sin_poly_d(double x, double x2) {
#pragma clang fp contract(off)
  const double s1 = -0x1.555545995a603p-3;
  const double s2 =  0x1.1107605230bc4p-7;
  const double s3 = -0x1.994eb3774cf24p-13;
  double x3  = x * x2;
  double s1v = __builtin_fma(x2, s3, s2);
  double x7  = x3 * x2;
  double s   = __builtin_fma(x3, s1, x);
  return __builtin_fma(x7, s1v, s);
}

__device__ __forceinline__ double cos_poly_d(double x2) {
#pragma clang fp contract(off)
  const double c0 =  1.0;
  const double c1 = -0x1.ffffffd0c621cp-2;
  const double c2 =  0x1.55553e1068f19p-5;
  const double c3 = -0x1.6c087e89a359dp-10;
  const double c4 =  0x1.99343027bf8c3p-16;
  double x4  = x2 * x2;
  double c2v = __builtin_fma(x2, c4, c3);
  double c1v = __builtin_fma(x2, c1, c0);
  double x6  = x4 * x2;
  double cv  = __builtin_fma(x4, c2, c1v);
  return __builtin_fma(x6, c2v, cv);
}

// Bit-exact port of glibc (>=2.28) __sinf/__cosf for 0 <= y < 2^12.
// Verified absmax == 0.0 on hardware (Rounds 2-4).
__device__ __forceinline__ void sincosf_glibc(float y, float& sf, float& cf) {
#pragma clang fp contract(off)
  const double hpi_inv = 0x1.45F306DC9C883p+23;
  const double hpi     = 0x1.921FB54442D18p0;
  const double pi63    = 0x1.921FB54442D18p-62;
  u32 xi = __float_as_uint(y);
  u32 abstop = (xi >> 20) & 0x7ffu;
  double x = (double)y;
  if (abstop < 0x398u) { sf = y; cf = 1.0f; return; }
  if (abstop < 0x3f4u) {
    double x2 = x * x;
    sf = (float)sin_poly_d(x, x2);
    cf = (float)cos_poly_d(x2);
    return;
  }
  int n;
  double xr;
  if (abstop < 0x42fu) {                         // reduce_fast
    double r = x * hpi_inv;
    n = (((int)r) + 0x800000) >> 24;
    xr = __builtin_fma(-(double)n, hpi, x);
  } else {                                       // reduce_large
    int idx = (xi >> 26) & 15;
    int sh  = (xi >> 23) & 7;
    u32 xm  = ((xi & 0xffffffu) | 0x800000u) << sh;
    u64 res0 = (u64)(u32)(xm * g_inv_pio4[idx]);
    u64 res1 = (u64)xm * (u64)g_inv_pio4[idx + 4];
    u64 res2 = (u64)xm * (u64)g_inv_pio4[idx + 8];
    res0 = ((res2 >> 32) | (res0 << 32)) + res1;
    u64 nn = (res0 + (1ull << 61)) >> 62;
    res0 -= nn << 62;
    double xd = (double)(long long)res0;
    xr = xd * pi63;
    n = (int)nn;
  }
  double x2 = xr * xr;
  double sp = sin_poly_d(xr, x2);
  double cp = cos_poly_d(x2);
  float spf = (float)sp, cpf = (float)cp;
  bool flip = (n & 2) != 0;
  float sres, cres;
  if (n & 1) {
    sres = flip ? -cpf : cpf;
    cres = flip ?  spf : -spf;
  } else {
    sres = flip ? -spf : spf;
    cres = flip ? -cpf : cpf;
  }
  sf = sres; cf = cres;
}

// Wave-autonomous + software-pipelined: each wave grid-strides over rows.
// After decoding row r (which frees the load buffer v[]), the wave issues
// all 16 loads of row r+stride BEFORE the sincos/encode/store of row r, so
// next-row loads are in flight under the compute phase. Stores are
// nontemporal (output is never re-read; keep L3 for the input stream).
__global__ __launch_bounds__(256, 4) void spike_rope_kernel(
    const float* __restrict__ xin, const int* __restrict__ position,
    float* __restrict__ outp, ThetaArr th, int batch)
{
#pragma clang fp contract(off)
  const int lane = (int)(threadIdx.x & 63u);
  const int wid  = (int)(threadIdx.x >> 6);
  const int nw   = (int)gridDim.x * 4;     // total waves
  int row = (int)blockIdx.x * 4 + wid;
  if (row >= batch) return;

  const int grp = lane >> 3;        // element sub-index within chunk (0..7)
  const int sub = lane & 7;         // 4-pulse slot within element (0..7)
  const int j0  = sub << 2;
  const int shN = 28 - j0;          // nibble placement shift (decode)
  const int sh0 = 31 - j0;          // first bit shift (encode)
  const int dsrc = sub << 3;        // decode route source lane

  const v4u* gx = (const v4u*)xin;
  v4u* gy = (v4u*)outp;

  // ---- prologue: load first row (coalesced 1KiB/instr) ----
  v4u v[16];
  {
    const v4u* rp = gx + (size_t)row * 1024;
#pragma unroll
    for (int s = 0; s < 16; ++s) v[s] = rp[s * 64 + lane];
  }

  for (;;) {
    // ---- decode current row from v[] (in-register transpose) ----
    u32 x1w = 0, x2w = 0;
#pragma unroll
    for (int s = 0; s < 16; ++s) {
      v4u q = v[s];
      u32 nib = (((q.x >> 23) & 1u) << 3) | (((q.y >> 23) & 1u) << 2) |
                (((q.z >> 23) & 1u) << 1) | ((q.w >> 23) & 1u);
      u32 part = nib << shN;
      part |= (u32)__shfl_xor((int)part, 1, 64);
      part |= (u32)__shfl_xor((int)part, 2, 64);
      part |= (u32)__shfl_xor((int)part, 4, 64);
      u32 full = (u32)__shfl((int)part, dsrc, 64);
      if (s < 8) { if (grp == s)     x1w = full; }
      else       { if (grp == s - 8) x2w = full; }
    }

    // ---- prefetch next row into v[] (overlaps sincos + stores) ----
    const int nrow = row + nw;
    const bool have_next = (nrow < batch);
    if (have_next) {
      const v4u* rp = gx + (size_t)nrow * 1024;
#pragma unroll
      for (int s = 0; s < 16; ++s) v[s] = rp[s * 64 + lane];
    }

    // ---- bit-exact fp32 RoPE (verified path, unchanged) ----
    float pf = (float)position[row];   // exact int->f32
    float ang = pf * th.t[lane];       // single f32 mul
    float sv, cv;
    sincosf_glibc(ang, sv, cv);
    float x1 = __uint_as_float(x1w);
    float x2 = __uint_as_float(x2w);
    // reference: r1 = x1*cos + (-x2)*sin ; r2 = x2*cos + x1*sin (NO fma)
    float r1 = (x1 * cv) + ((-x2) * sv);
    float r2 = (x2 * cv) + (x1 * sv);
    u32 o1 = __float_as_uint(r1);
    u32 o2 = __float_as_uint(r2);

    // ---- in-register transpose + encode + nontemporal store ----
    v4u* orow = gy + (size_t)row * 1024;
#pragma unroll
    for (int s = 0; s < 16; ++s) {
      int sl = ((s & 7) << 3) + grp;           // source lane holding element
      u32 ow = (u32)__shfl((int)(s < 8 ? o1 : o2), sl, 64);
      v4u w;
      w.x = ((ow >> sh0) & 1u)       ? 0x3f800000u : 0u;
      w.y = ((ow >> (sh0 - 1)) & 1u) ? 0x3f800000u : 0u;
      w.z = ((ow >> (sh0 - 2)) & 1u) ? 0x3f800000u : 0u;
      w.w = ((ow >> (sh0 - 3)) & 1u) ? 0x3f800000u : 0u;
      __builtin_nontemporal_store(w, &orow[s * 64 + lane]);
    }

    if (!have_next) break;
    row = nrow;
  }
}

extern "C" void kernel_launch(void* const* d_in, const int* in_sizes, int n_in,
                              void* d_out, int out_size, void* d_ws, size_t ws_size,
                              hipStream_t stream) {
  const float* x = (const float*)d_in[0];
  const int* position = (const int*)d_in[1];
  float* out = (float*)d_out;
  int batch = in_sizes[1];

  // theta[i] = powf(10000f, -2f*i/128f) via the runtime glibc powf.
  // volatile fn-pointer defeats LLVM constant folding.
  ThetaArr th;
  float (*volatile pfn)(float, float) = &powf;
  for (int i = 0; i < 64; ++i) {
    float e = (-2.0f * (float)i) / 128.0f;
    th.t[i] = pfn(10000.0f, e);
  }

  // 1024 blocks x 4 waves = 4096 waves (16/CU at 4 waves/SIMD);
  // each wave grid-strides over ~4 rows -> 3 fully-pipelined iterations.
  int blocks = (batch + 3) / 4;
  if (blocks > 1024) blocks = 1024;
  spike_rope_kernel<<<blocks, 256, 0, stream>>>(x, position, out, th, batch);
}